// Round 1
// baseline (454.403 us; speedup 1.0000x reference)
//
#include <hip/hip_runtime.h>

static constexpr int NN = 50000;   // nodes
static constexpr int NE = 800000;  // edges
static constexpr int CH = 64;      // in/hidden channels

// ---------------- degree count ----------------
__global__ __launch_bounds__(256) void k_deg(const int* __restrict__ dst,
                                             int* __restrict__ deg) {
    int e = blockIdx.x * 256 + threadIdx.x;
    if (e < NE) atomicAdd(&deg[dst[e]], 1);
}

// ---------------- 1/max(deg,1) ----------------
__global__ __launch_bounds__(256) void k_inv(const int* __restrict__ deg,
                                             float* __restrict__ inv) {
    int n = blockIdx.x * 256 + threadIdx.x;
    if (n < NN) inv[n] = 1.0f / fmaxf((float)deg[n], 1.0f);
}

// ---------------- layer-1 scatter: agg[dst] += x[src], 64 ch ----------------
// one wave (64 lanes) per edge: lane c handles channel c -> coalesced 256B row
__global__ __launch_bounds__(256) void k_scat1(const int* __restrict__ src,
                                               const int* __restrict__ dst,
                                               const float* __restrict__ x,
                                               float* __restrict__ agg) {
    int t = blockIdx.x * 256 + threadIdx.x;
    int e = t >> 6;
    int c = t & 63;
    if (e >= NE) return;
    int s = src[e];
    int d = dst[e];
    atomicAdd(&agg[d * CH + c], x[s * CH + c]);
}

// ---------------- layer-1 finalize: h = relu(mean@W1l^T + b1 + x@W1r^T) -----
// block = 256 threads = 4 nodes x 64 output channels; weights staged in LDS
// transposed (WT[c][o]) so the inner-loop read is lane-contiguous (no bank
// conflicts); per-node feature rows staged in LDS (broadcast reads are free).
__global__ __launch_bounds__(256) void k_l1(const float* __restrict__ x,
                                            const float* __restrict__ agg,
                                            const float* __restrict__ inv,
                                            const float* __restrict__ W1l,
                                            const float* __restrict__ W1r,
                                            const float* __restrict__ b1,
                                            float* __restrict__ h) {
    __shared__ float WlT[64 * 64];
    __shared__ float WrT[64 * 64];
    __shared__ float mrow[4][64];
    __shared__ float xrow[4][64];

    int tid = threadIdx.x;
    // LDS-coalesced weight load: WT[i] = W[o*64+c] with i = c*64+o
    for (int i = tid; i < 64 * 64; i += 256) {
        int c = i >> 6;
        int o = i & 63;
        WlT[i] = W1l[o * 64 + c];
        WrT[i] = W1r[o * 64 + c];
    }

    int nl = tid >> 6;      // node within block
    int o  = tid & 63;      // output channel
    int n  = blockIdx.x * 4 + nl;
    if (n < NN) {
        float id = inv[n];
        mrow[nl][o] = agg[n * CH + o] * id;
        xrow[nl][o] = x[n * CH + o];
    }
    __syncthreads();
    if (n >= NN) return;

    float acc = b1[o];
#pragma unroll
    for (int c = 0; c < 64; ++c) {
        acc += mrow[nl][c] * WlT[c * 64 + o] + xrow[nl][c] * WrT[c * 64 + o];
    }
    h[n * CH + o] = fmaxf(acc, 0.0f);
}

// ---------------- layer-2 node-local: hl2 = h@W2l^T ; out = b2 + h@W2r^T ----
__global__ __launch_bounds__(256) void k_l2a(const float* __restrict__ h,
                                             const float* __restrict__ W2l,
                                             const float* __restrict__ W2r,
                                             const float* __restrict__ b2,
                                             float* __restrict__ hl2,
                                             float* __restrict__ out) {
    __shared__ float wl[128];
    __shared__ float wr[128];
    int tid = threadIdx.x;
    if (tid < 128) {
        wl[tid] = W2l[tid];
        wr[tid] = W2r[tid];
    }
    __syncthreads();
    int n = blockIdx.x * 256 + tid;
    if (n >= NN) return;

    const float4* hp = (const float4*)(h + (size_t)n * CH);
    float a0 = 0.f, a1 = 0.f, r0 = 0.f, r1 = 0.f;
#pragma unroll
    for (int i = 0; i < 16; ++i) {
        float4 v = hp[i];
        a0 += v.x * wl[4 * i + 0] + v.y * wl[4 * i + 1] + v.z * wl[4 * i + 2] + v.w * wl[4 * i + 3];
        a1 += v.x * wl[64 + 4 * i + 0] + v.y * wl[64 + 4 * i + 1] + v.z * wl[64 + 4 * i + 2] + v.w * wl[64 + 4 * i + 3];
        r0 += v.x * wr[4 * i + 0] + v.y * wr[4 * i + 1] + v.z * wr[4 * i + 2] + v.w * wr[4 * i + 3];
        r1 += v.x * wr[64 + 4 * i + 0] + v.y * wr[64 + 4 * i + 1] + v.z * wr[64 + 4 * i + 2] + v.w * wr[64 + 4 * i + 3];
    }
    hl2[n * 2 + 0] = a0;
    hl2[n * 2 + 1] = a1;
    out[n * 2 + 0] = b2[0] + r0;
    out[n * 2 + 1] = b2[1] + r1;
}

// ---------------- layer-2 scatter (2 ch/edge) -------------------------------
__global__ __launch_bounds__(256) void k_scat2(const int* __restrict__ src,
                                               const int* __restrict__ dst,
                                               const float* __restrict__ hl2,
                                               const float* __restrict__ inv,
                                               float* __restrict__ out) {
    int t = blockIdx.x * 256 + threadIdx.x;
    int e = t >> 1;
    int c = t & 1;
    if (e >= NE) return;
    int s = src[e];
    int d = dst[e];
    atomicAdd(&out[d * 2 + c], hl2[s * 2 + c] * inv[d]);
}

extern "C" void kernel_launch(void* const* d_in, const int* in_sizes, int n_in,
                              void* d_out, int out_size, void* d_ws, size_t ws_size,
                              hipStream_t stream) {
    const float* x   = (const float*)d_in[0];
    const int*   ei  = (const int*)d_in[1];
    const float* W1l = (const float*)d_in[2];
    const float* W1r = (const float*)d_in[3];
    const float* b1  = (const float*)d_in[4];
    const float* W2l = (const float*)d_in[5];
    const float* W2r = (const float*)d_in[6];
    const float* b2  = (const float*)d_in[7];
    float* out = (float*)d_out;

    const int* src = ei;        // edge_index[0, :]
    const int* dst = ei + NE;   // edge_index[1, :]

    // workspace layout (f32 units)
    char* ws = (char*)d_ws;
    int*   deg = (int*)ws;                         // 50048 ints (padded)
    float* inv = (float*)(ws + 50048 * 4);         // 50048 floats
    float* agg = (float*)(ws + 2 * 50048 * 4);     // NN*CH
    float* h   = agg + (size_t)NN * CH;            // NN*CH
    float* hl2 = h + (size_t)NN * CH;              // NN*2
    // total ~26.2 MB

    // per-call zeroing (harness does not re-poison between replays)
    hipMemsetAsync(deg, 0, 50048 * 4, stream);
    hipMemsetAsync(agg, 0, (size_t)NN * CH * 4, stream);

    k_deg<<<(NE + 255) / 256, 256, 0, stream>>>(dst, deg);
    k_inv<<<(NN + 255) / 256, 256, 0, stream>>>(deg, inv);
    k_scat1<<<(NE * CH) / 256, 256, 0, stream>>>(src, dst, x, agg);
    k_l1<<<(NN + 3) / 4, 256, 0, stream>>>(x, agg, inv, W1l, W1r, b1, h);
    k_l2a<<<(NN + 255) / 256, 256, 0, stream>>>(h, W2l, W2r, b2, hl2, out);
    k_scat2<<<(2 * NE + 255) / 256, 256, 0, stream>>>(src, dst, hl2, inv, out);
}

// Round 2
// 310.654 us; speedup vs baseline: 1.4627x; 1.4627x over previous
//
#include <hip/hip_runtime.h>

static constexpr int NN = 50000;   // nodes
static constexpr int NE = 800000;  // edges
static constexpr int CH = 64;      // in/hidden channels

// ---------------- degree count ----------------
__global__ __launch_bounds__(256) void k_deg(const int* __restrict__ dst,
                                             int* __restrict__ deg) {
    int e = blockIdx.x * 256 + threadIdx.x;
    if (e < NE) atomicAdd(&deg[dst[e]], 1);
}

// ---------------- layer-1 scatter: agg[dst] += x[src], 64 ch ----------------
// one wave (64 lanes) per edge: lane c handles channel c -> coalesced 256B row
__global__ __launch_bounds__(256) void k_scat1(const int* __restrict__ src,
                                               const int* __restrict__ dst,
                                               const float* __restrict__ x,
                                               float* __restrict__ agg) {
    int t = blockIdx.x * 256 + threadIdx.x;
    int e = t >> 6;
    int c = t & 63;
    if (e >= NE) return;
    int s = src[e];
    int d = dst[e];
    atomicAdd(&agg[d * CH + c], x[s * CH + c]);
}

// ---------------- fused: layer-1 finalize + layer-2 node-local projections --
// One wave (64 lanes) per block; weights live in REGISTERS (lane o holds row o
// of W1l and W1r -> 128 VGPRs), loaded once per wave. Node rows are staged
// through a tiny LDS buffer and consumed as float4 broadcast reads (conflict-
// free). Epilogue folds the layer-2 projections (h@W2l^T, h@W2r^T: 64->2) via
// a 64-lane butterfly reduction, so h never touches global memory.
__global__ __launch_bounds__(64, 3) void k_fused(
        const float* __restrict__ x, const float* __restrict__ agg,
        const int* __restrict__ deg,
        const float* __restrict__ W1l, const float* __restrict__ W1r,
        const float* __restrict__ b1,
        const float* __restrict__ W2l, const float* __restrict__ W2r,
        const float* __restrict__ b2,
        float* __restrict__ hl2, float* __restrict__ out) {
    __shared__ float4 bufm[16];   // mean row (64 f32)
    __shared__ float4 bufx[16];   // x row    (64 f32)

    const int lane = threadIdx.x;  // 0..63

    // weights -> registers (once per wave; ~3k waves total so the scattered
    // read pattern is negligible, unlike the old per-block LDS transpose)
    float4 wl[16], wr[16];
    const float4* wlp = (const float4*)(W1l + lane * CH);
    const float4* wrp = (const float4*)(W1r + lane * CH);
#pragma unroll
    for (int i = 0; i < 16; ++i) { wl[i] = wlp[i]; wr[i] = wrp[i]; }
    const float bias = b1[lane];
    const float w2l0 = W2l[lane], w2l1 = W2l[64 + lane];
    const float w2r0 = W2r[lane], w2r1 = W2r[64 + lane];
    const float b20 = b2[0], b21 = b2[1];

    // contiguous node chunk per wave -> streaming-friendly global reads
    constexpr int NPER = 17;                       // ceil(50000/2942)
    const int n0 = blockIdx.x * NPER;
    const int n1 = min(n0 + NPER, NN);

    for (int n = n0; n < n1; ++n) {
        const float idn = 1.0f / fmaxf((float)deg[n], 1.0f);
        ((float*)bufm)[lane] = agg[n * CH + lane] * idn;
        ((float*)bufx)[lane] = x[n * CH + lane];
        __syncthreads();   // single-wave block: ~free, forces lgkmcnt drain

        float acc = bias;
#pragma unroll
        for (int i = 0; i < 16; ++i) {
            float4 m = bufm[i];
            float4 v = bufx[i];
            acc += m.x * wl[i].x + m.y * wl[i].y + m.z * wl[i].z + m.w * wl[i].w;
            acc += v.x * wr[i].x + v.y * wr[i].y + v.z * wr[i].z + v.w * wr[i].w;
        }
        const float h = fmaxf(acc, 0.0f);   // relu (dropout = identity in eval)

        // layer-2 node-local partials, butterfly-reduced across the wave
        float a0 = h * w2l0, a1 = h * w2l1, r0 = h * w2r0, r1 = h * w2r1;
#pragma unroll
        for (int off = 32; off > 0; off >>= 1) {
            a0 += __shfl_xor(a0, off);
            a1 += __shfl_xor(a1, off);
            r0 += __shfl_xor(r0, off);
            r1 += __shfl_xor(r1, off);
        }
        if (lane == 0) {
            *(float2*)(hl2 + (size_t)n * 2) = make_float2(a0, a1);
            *(float2*)(out + (size_t)n * 2) = make_float2(b20 + r0, b21 + r1);
        }
        __syncthreads();   // protect buf reuse next iteration
    }
}

// ---------------- layer-2 scatter (2 ch/edge) -------------------------------
__global__ __launch_bounds__(256) void k_scat2(const int* __restrict__ src,
                                               const int* __restrict__ dst,
                                               const float* __restrict__ hl2,
                                               const int* __restrict__ deg,
                                               float* __restrict__ out) {
    int t = blockIdx.x * 256 + threadIdx.x;
    int e = t >> 1;
    int c = t & 1;
    if (e >= NE) return;
    int s = src[e];
    int d = dst[e];
    float idn = 1.0f / fmaxf((float)deg[d], 1.0f);
    atomicAdd(&out[d * 2 + c], hl2[s * 2 + c] * idn);
}

extern "C" void kernel_launch(void* const* d_in, const int* in_sizes, int n_in,
                              void* d_out, int out_size, void* d_ws, size_t ws_size,
                              hipStream_t stream) {
    const float* x   = (const float*)d_in[0];
    const int*   ei  = (const int*)d_in[1];
    const float* W1l = (const float*)d_in[2];
    const float* W1r = (const float*)d_in[3];
    const float* b1  = (const float*)d_in[4];
    const float* W2l = (const float*)d_in[5];
    const float* W2r = (const float*)d_in[6];
    const float* b2  = (const float*)d_in[7];
    float* out = (float*)d_out;

    const int* src = ei;        // edge_index[0, :]
    const int* dst = ei + NE;   // edge_index[1, :]

    // workspace layout
    char* ws = (char*)d_ws;
    int*   deg = (int*)ws;                        // 50048 ints
    float* agg = (float*)(ws + 50048 * 4);        // NN*CH f32
    float* hl2 = agg + (size_t)NN * CH;           // NN*2 f32

    // per-call zeroing (harness does not re-poison between replays)
    hipMemsetAsync(deg, 0, 50048 * 4, stream);
    hipMemsetAsync(agg, 0, (size_t)NN * CH * 4, stream);

    k_deg<<<(NE + 255) / 256, 256, 0, stream>>>(dst, deg);
    k_scat1<<<(NE * CH) / 256, 256, 0, stream>>>(src, dst, x, agg);

    constexpr int NPER = 17;
    k_fused<<<(NN + NPER - 1) / NPER, 64, 0, stream>>>(
        x, agg, deg, W1l, W1r, b1, W2l, W2r, b2, hl2, out);

    k_scat2<<<(2 * NE + 255) / 256, 256, 0, stream>>>(src, dst, hl2, deg, out);
}

// Round 3
// 249.229 us; speedup vs baseline: 1.8232x; 1.2465x over previous
//
#include <hip/hip_runtime.h>

static constexpr int NN = 50000;   // nodes
static constexpr int NE = 800000;  // edges
static constexpr int CH = 64;      // in/hidden channels

// ---------------- degree histogram ----------------
__global__ __launch_bounds__(256) void k_deg(const int* __restrict__ dst,
                                             int* __restrict__ deg) {
    int e = blockIdx.x * 256 + threadIdx.x;
    if (e < NE) atomicAdd(&deg[dst[e]], 1);
}

// ---------------- exclusive prefix sum (single block, 1024 thr) -------------
// rowptr[0..NN] = exclusive scan of deg; cursor[i] = rowptr[i] (place cursors)
__global__ __launch_bounds__(1024) void k_scan(const int* __restrict__ deg,
                                               int* __restrict__ rowptr,
                                               int* __restrict__ cursor) {
    __shared__ int wsum[16];
    __shared__ int carry;
    const int tid  = threadIdx.x;
    const int lane = tid & 63;
    const int w    = tid >> 6;
    if (tid == 0) { carry = 0; rowptr[0] = 0; }
    __syncthreads();
    for (int base = 0; base < NN; base += 1024) {
        const int i = base + tid;
        const int v = (i < NN) ? deg[i] : 0;
        int s = v;
#pragma unroll
        for (int off = 1; off < 64; off <<= 1) {
            int t = __shfl_up(s, off);
            if (lane >= off) s += t;
        }
        if (lane == 63) wsum[w] = s;
        __syncthreads();
        if (w == 0) {
            int ws = (lane < 16) ? wsum[lane] : 0;
#pragma unroll
            for (int off = 1; off < 16; off <<= 1) {
                int t = __shfl_up(ws, off);
                if (lane >= off) ws += t;
            }
            if (lane < 16) wsum[lane] = ws;
        }
        __syncthreads();
        const int wbase = (w == 0) ? 0 : wsum[w - 1];
        const int excl  = carry + wbase + (s - v);   // exclusive prefix
        if (i < NN) {
            rowptr[i + 1] = excl + v;
            cursor[i]     = excl;
        }
        __syncthreads();
        if (tid == 0) carry += wsum[15];
        __syncthreads();
    }
}

// ---------------- bucket-place: col[] = src ids grouped by dst --------------
__global__ __launch_bounds__(256) void k_place(const int* __restrict__ src,
                                               const int* __restrict__ dst,
                                               int* __restrict__ cursor,
                                               int* __restrict__ col) {
    int e = blockIdx.x * 256 + threadIdx.x;
    if (e >= NE) return;
    int pos = atomicAdd(&cursor[dst[e]], 1);
    col[pos] = src[e];
}

// ---------------- layer-1 CSR mean-aggregate: mean[n] = avg(x[col]) ---------
// one wave per node: lane c owns channel c -> 256B coalesced row gathers
__global__ __launch_bounds__(256) void k_agg1(const int* __restrict__ rowptr,
                                              const int* __restrict__ col,
                                              const float* __restrict__ x,
                                              float* __restrict__ mean) {
    const int node = blockIdx.x * 4 + (threadIdx.x >> 6);
    const int lane = threadIdx.x & 63;
    if (node >= NN) return;
    const int beg = rowptr[node], end = rowptr[node + 1];
    float acc = 0.0f;
    int i = beg;
    for (; i + 1 < end; i += 2) {          // 2-way unroll for latency overlap
        int s0 = col[i], s1 = col[i + 1];
        acc += x[s0 * CH + lane];
        acc += x[s1 * CH + lane];
    }
    if (i < end) acc += x[col[i] * CH + lane];
    const float inv = (end > beg) ? 1.0f / (float)(end - beg) : 0.0f;
    mean[(size_t)node * CH + lane] = acc * inv;
}

// ---------------- fused: layer-1 finalize + layer-2 node-local projections --
// weights in registers (lane o holds W1l/W1r row o), node rows via LDS
// broadcast; epilogue butterfly-reduces the 64->2 layer-2 projections.
__global__ __launch_bounds__(64, 3) void k_fused(
        const float* __restrict__ x, const float* __restrict__ mean,
        const float* __restrict__ W1l, const float* __restrict__ W1r,
        const float* __restrict__ b1,
        const float* __restrict__ W2l, const float* __restrict__ W2r,
        const float* __restrict__ b2,
        float* __restrict__ hl2, float* __restrict__ out) {
    __shared__ float4 bufm[16];
    __shared__ float4 bufx[16];

    const int lane = threadIdx.x;  // 0..63

    float4 wl[16], wr[16];
    const float4* wlp = (const float4*)(W1l + lane * CH);
    const float4* wrp = (const float4*)(W1r + lane * CH);
#pragma unroll
    for (int i = 0; i < 16; ++i) { wl[i] = wlp[i]; wr[i] = wrp[i]; }
    const float bias = b1[lane];
    const float w2l0 = W2l[lane], w2l1 = W2l[64 + lane];
    const float w2r0 = W2r[lane], w2r1 = W2r[64 + lane];
    const float b20 = b2[0], b21 = b2[1];

    constexpr int NPER = 17;
    const int n0 = blockIdx.x * NPER;
    const int n1 = min(n0 + NPER, NN);

    for (int n = n0; n < n1; ++n) {
        ((float*)bufm)[lane] = mean[(size_t)n * CH + lane];
        ((float*)bufx)[lane] = x[(size_t)n * CH + lane];
        __syncthreads();

        float acc = bias;
#pragma unroll
        for (int i = 0; i < 16; ++i) {
            float4 m = bufm[i];
            float4 v = bufx[i];
            acc += m.x * wl[i].x + m.y * wl[i].y + m.z * wl[i].z + m.w * wl[i].w;
            acc += v.x * wr[i].x + v.y * wr[i].y + v.z * wr[i].z + v.w * wr[i].w;
        }
        const float h = fmaxf(acc, 0.0f);   // relu (dropout = identity in eval)

        float a0 = h * w2l0, a1 = h * w2l1, r0 = h * w2r0, r1 = h * w2r1;
#pragma unroll
        for (int off = 32; off > 0; off >>= 1) {
            a0 += __shfl_xor(a0, off);
            a1 += __shfl_xor(a1, off);
            r0 += __shfl_xor(r0, off);
            r1 += __shfl_xor(r1, off);
        }
        if (lane == 0) {
            *(float2*)(hl2 + (size_t)n * 2) = make_float2(a0, a1);
            *(float2*)(out + (size_t)n * 2) = make_float2(b20 + r0, b21 + r1);
        }
        __syncthreads();
    }
}

// ---------------- layer-2 CSR mean-aggregate + add into out -----------------
// thread per (node, channel): gathers hl2 (400 KB, L2-resident)
__global__ __launch_bounds__(256) void k_agg2(const int* __restrict__ rowptr,
                                              const int* __restrict__ col,
                                              const float* __restrict__ hl2,
                                              float* __restrict__ out) {
    int t = blockIdx.x * 256 + threadIdx.x;
    int n = t >> 1;
    int c = t & 1;
    if (n >= NN) return;
    const int beg = rowptr[n], end = rowptr[n + 1];
    float acc = 0.0f;
    for (int i = beg; i < end; ++i) acc += hl2[2 * col[i] + c];
    const float inv = (end > beg) ? 1.0f / (float)(end - beg) : 0.0f;
    out[2 * n + c] += acc * inv;
}

extern "C" void kernel_launch(void* const* d_in, const int* in_sizes, int n_in,
                              void* d_out, int out_size, void* d_ws, size_t ws_size,
                              hipStream_t stream) {
    const float* x   = (const float*)d_in[0];
    const int*   ei  = (const int*)d_in[1];
    const float* W1l = (const float*)d_in[2];
    const float* W1r = (const float*)d_in[3];
    const float* b1  = (const float*)d_in[4];
    const float* W2l = (const float*)d_in[5];
    const float* W2r = (const float*)d_in[6];
    const float* b2  = (const float*)d_in[7];
    float* out = (float*)d_out;

    const int* src = ei;        // edge_index[0, :]
    const int* dst = ei + NE;   // edge_index[1, :]

    // workspace layout (all fully rewritten each call except deg -> memset)
    char* ws = (char*)d_ws;
    int*   deg    = (int*)ws;                          // 50048
    int*   rowptr = deg + 50048;                       // 50051 (pad 50052)
    int*   cursor = rowptr + 50052;                    // 50048
    int*   col    = cursor + 50048;                    // NE
    float* mean   = (float*)(col + NE);                // NN*CH
    float* hl2    = mean + (size_t)NN * CH;            // NN*2
    // total ~16.9 MB

    hipMemsetAsync(deg, 0, 50048 * 4, stream);

    k_deg  <<<(NE + 255) / 256, 256, 0, stream>>>(dst, deg);
    k_scan <<<1, 1024, 0, stream>>>(deg, rowptr, cursor);
    k_place<<<(NE + 255) / 256, 256, 0, stream>>>(src, dst, cursor, col);
    k_agg1 <<<(NN + 3) / 4, 256, 0, stream>>>(rowptr, col, x, mean);

    constexpr int NPER = 17;
    k_fused<<<(NN + NPER - 1) / NPER, 64, 0, stream>>>(
        x, mean, W1l, W1r, b1, W2l, W2r, b2, hl2, out);

    k_agg2 <<<(2 * NN + 255) / 256, 256, 0, stream>>>(rowptr, col, hl2, out);
}

// Round 4
// 209.400 us; speedup vs baseline: 2.1700x; 1.1902x over previous
//
#include <hip/hip_runtime.h>

static constexpr int NN = 50000;   // nodes
static constexpr int NE = 800000;  // edges
static constexpr int CH = 64;      // in/hidden channels
static constexpr int NB = (NN + 255) / 256;   // 196 scan blocks

// ---------------- degree histogram ----------------
__global__ __launch_bounds__(256) void k_deg(const int* __restrict__ dst,
                                             int* __restrict__ deg) {
    int e = blockIdx.x * 256 + threadIdx.x;
    if (e < NE) atomicAdd(&deg[dst[e]], 1);
}

// ---------------- scan phase 1: per-block sums ------------------------------
__global__ __launch_bounds__(256) void k_bsum(const int* __restrict__ deg,
                                              int* __restrict__ bs) {
    int i = blockIdx.x * 256 + threadIdx.x;
    int v = (i < NN) ? deg[i] : 0;
#pragma unroll
    for (int off = 32; off > 0; off >>= 1) v += __shfl_xor(v, off);
    __shared__ int ws[4];
    if ((threadIdx.x & 63) == 0) ws[threadIdx.x >> 6] = v;
    __syncthreads();
    if (threadIdx.x == 0) bs[blockIdx.x] = ws[0] + ws[1] + ws[2] + ws[3];
}

// ---------------- scan phase 2: exclusive scan of the 196 block sums --------
__global__ __launch_bounds__(256) void k_bscan(int* __restrict__ bs) {
    int tid = threadIdx.x, lane = tid & 63, w = tid >> 6;
    __shared__ int wsum[4];
    int v = (tid < NB) ? bs[tid] : 0;
    int s = v;
#pragma unroll
    for (int off = 1; off < 64; off <<= 1) {
        int t = __shfl_up(s, off);
        if (lane >= off) s += t;
    }
    if (lane == 63) wsum[w] = s;
    __syncthreads();
    if (tid == 0) {
        int c = 0;
#pragma unroll
        for (int k = 0; k < 4; ++k) { int t = wsum[k]; wsum[k] = c; c += t; }
    }
    __syncthreads();
    if (tid < NB) bs[tid] = wsum[w] + s - v;   // exclusive offsets
}

// ---------------- scan phase 3: block rescan -> rowptr / cursor -------------
__global__ __launch_bounds__(256) void k_rescan(const int* __restrict__ deg,
                                                const int* __restrict__ bs,
                                                int* __restrict__ rowptr,
                                                int* __restrict__ cursor) {
    int tid = threadIdx.x, lane = tid & 63, w = tid >> 6;
    int i = blockIdx.x * 256 + tid;
    __shared__ int wsum[4];
    int v = (i < NN) ? deg[i] : 0;
    int s = v;
#pragma unroll
    for (int off = 1; off < 64; off <<= 1) {
        int t = __shfl_up(s, off);
        if (lane >= off) s += t;
    }
    if (lane == 63) wsum[w] = s;
    __syncthreads();
    if (tid == 0) {
        int c = 0;
#pragma unroll
        for (int k = 0; k < 4; ++k) { int t = wsum[k]; wsum[k] = c; c += t; }
    }
    __syncthreads();
    if (i < NN) {
        int excl = bs[blockIdx.x] + wsum[w] + s - v;
        rowptr[i] = excl;
        cursor[i] = excl;
    }
    if (blockIdx.x == 0 && tid == 0) rowptr[NN] = NE;
}

// ---------------- bucket-place: col[] = src ids grouped by dst --------------
__global__ __launch_bounds__(256) void k_place(const int* __restrict__ src,
                                               const int* __restrict__ dst,
                                               int* __restrict__ cursor,
                                               int* __restrict__ col) {
    int e = blockIdx.x * 256 + threadIdx.x;
    if (e >= NE) return;
    int pos = atomicAdd(&cursor[dst[e]], 1);
    col[pos] = src[e];
}

// ---------------- layer-1 CSR mean-aggregate: mean[n] = avg(x[col]) ---------
// wave per node, lane = channel; 8 row-gathers in flight for latency overlap
__global__ __launch_bounds__(256) void k_agg1(const int* __restrict__ rowptr,
                                              const int* __restrict__ col,
                                              const float* __restrict__ x,
                                              float* __restrict__ mean) {
    const int node = blockIdx.x * 4 + (threadIdx.x >> 6);
    const int lane = threadIdx.x & 63;
    if (node >= NN) return;
    const int beg = rowptr[node], end = rowptr[node + 1];
    float acc = 0.0f;
    int i = beg;
    for (; i + 8 <= end; i += 8) {
        int c0 = col[i + 0], c1 = col[i + 1], c2 = col[i + 2], c3 = col[i + 3];
        int c4 = col[i + 4], c5 = col[i + 5], c6 = col[i + 6], c7 = col[i + 7];
        float v0 = x[c0 * CH + lane], v1 = x[c1 * CH + lane];
        float v2 = x[c2 * CH + lane], v3 = x[c3 * CH + lane];
        float v4 = x[c4 * CH + lane], v5 = x[c5 * CH + lane];
        float v6 = x[c6 * CH + lane], v7 = x[c7 * CH + lane];
        acc += ((v0 + v1) + (v2 + v3)) + ((v4 + v5) + (v6 + v7));
    }
    for (; i < end; ++i) acc += x[col[i] * CH + lane];
    const float inv = (end > beg) ? 1.0f / (float)(end - beg) : 0.0f;
    mean[(size_t)node * CH + lane] = acc * inv;
}

// ---------------- fused: layer-1 finalize + layer-2 node-local projections --
// One wave per block. Weights register-resident (lane o holds W1l/W1r row o
// = 128 VGPRs; NO launch_bounds occupancy cap so they actually stay in regs).
// Node rows are wave-UNIFORM -> read via scalar loads (s_load_dwordx16) and
// consumed as the SGPR operand of v_fmac: zero LDS in the hot loop.
__global__ void k_fused(
        const float* __restrict__ x, const float* __restrict__ mean,
        const float* __restrict__ W1l, const float* __restrict__ W1r,
        const float* __restrict__ b1,
        const float* __restrict__ W2l, const float* __restrict__ W2r,
        const float* __restrict__ b2,
        float* __restrict__ hl2, float* __restrict__ out) {
    const int lane = threadIdx.x;  // 0..63

    float wl[CH], wr[CH];
    const float4* wlp = (const float4*)(W1l + lane * CH);
    const float4* wrp = (const float4*)(W1r + lane * CH);
#pragma unroll
    for (int i = 0; i < 16; ++i) {
        float4 a = wlp[i], b = wrp[i];
        wl[4 * i + 0] = a.x; wl[4 * i + 1] = a.y; wl[4 * i + 2] = a.z; wl[4 * i + 3] = a.w;
        wr[4 * i + 0] = b.x; wr[4 * i + 1] = b.y; wr[4 * i + 2] = b.z; wr[4 * i + 3] = b.w;
    }
    const float bias = b1[lane];
    const float w2l0 = W2l[lane], w2l1 = W2l[64 + lane];
    const float w2r0 = W2r[lane], w2r1 = W2r[64 + lane];
    const float b20 = b2[0], b21 = b2[1];

    constexpr int NPER = 8;
    const int n0 = blockIdx.x * NPER;
    const int n1 = min(n0 + NPER, NN);

    for (int n = n0; n < n1; ++n) {
        const float* mr = mean + (size_t)n * CH;   // wave-uniform address
        const float* xr = x + (size_t)n * CH;      // wave-uniform address
        float acc = bias;
#pragma unroll
        for (int c = 0; c < CH; ++c) {
            acc = fmaf(mr[c], wl[c], acc);
            acc = fmaf(xr[c], wr[c], acc);
        }
        const float h = fmaxf(acc, 0.0f);   // relu (dropout = identity in eval)

        float a0 = h * w2l0, a1 = h * w2l1, r0 = h * w2r0, r1 = h * w2r1;
#pragma unroll
        for (int off = 32; off > 0; off >>= 1) {
            a0 += __shfl_xor(a0, off);
            a1 += __shfl_xor(a1, off);
            r0 += __shfl_xor(r0, off);
            r1 += __shfl_xor(r1, off);
        }
        if (lane == 0) {
            *(float2*)(hl2 + (size_t)n * 2) = make_float2(a0, a1);
            *(float2*)(out + (size_t)n * 2) = make_float2(b20 + r0, b21 + r1);
        }
    }
}

// ---------------- layer-2 CSR mean-aggregate + add into out -----------------
// 8 lanes per node striding the bucket; float2 gathers of hl2 (L2-resident)
__global__ __launch_bounds__(256) void k_agg2(const int* __restrict__ rowptr,
                                              const int* __restrict__ col,
                                              const float2* __restrict__ hl2,
                                              float2* __restrict__ out) {
    int t = blockIdx.x * 256 + threadIdx.x;
    int node = t >> 3;
    int sl = t & 7;
    if (node >= NN) return;
    const int beg = rowptr[node], end = rowptr[node + 1];
    float ax = 0.0f, ay = 0.0f;
    for (int i = beg + sl; i < end; i += 8) {
        float2 v = hl2[col[i]];
        ax += v.x; ay += v.y;
    }
#pragma unroll
    for (int off = 4; off > 0; off >>= 1) {
        ax += __shfl_xor(ax, off);
        ay += __shfl_xor(ay, off);
    }
    if (sl == 0) {
        const float inv = (end > beg) ? 1.0f / (float)(end - beg) : 0.0f;
        float2 o = out[node];
        o.x += ax * inv;
        o.y += ay * inv;
        out[node] = o;
    }
}

extern "C" void kernel_launch(void* const* d_in, const int* in_sizes, int n_in,
                              void* d_out, int out_size, void* d_ws, size_t ws_size,
                              hipStream_t stream) {
    const float* x   = (const float*)d_in[0];
    const int*   ei  = (const int*)d_in[1];
    const float* W1l = (const float*)d_in[2];
    const float* W1r = (const float*)d_in[3];
    const float* b1  = (const float*)d_in[4];
    const float* W2l = (const float*)d_in[5];
    const float* W2r = (const float*)d_in[6];
    const float* b2  = (const float*)d_in[7];
    float* out = (float*)d_out;

    const int* src = ei;        // edge_index[0, :]
    const int* dst = ei + NE;   // edge_index[1, :]

    // workspace layout
    char* ws = (char*)d_ws;
    int*   deg    = (int*)ws;                          // 50048
    int*   rowptr = deg + 50048;                       // 50001 (pad 50052)
    int*   cursor = rowptr + 50052;                    // 50048
    int*   bs     = cursor + 50048;                    // 256
    int*   col    = bs + 256;                          // NE
    float* mean   = (float*)(col + NE);                // NN*CH
    float* hl2    = mean + (size_t)NN * CH;            // NN*2

    hipMemsetAsync(deg, 0, 50048 * 4, stream);

    k_deg   <<<(NE + 255) / 256, 256, 0, stream>>>(dst, deg);
    k_bsum  <<<NB, 256, 0, stream>>>(deg, bs);
    k_bscan <<<1, 256, 0, stream>>>(bs);
    k_rescan<<<NB, 256, 0, stream>>>(deg, bs, rowptr, cursor);
    k_place <<<(NE + 255) / 256, 256, 0, stream>>>(src, dst, cursor, col);
    k_agg1  <<<(NN + 3) / 4, 256, 0, stream>>>(rowptr, col, x, mean);

    constexpr int NPER = 8;
    k_fused<<<(NN + NPER - 1) / NPER, 64, 0, stream>>>(
        x, mean, W1l, W1r, b1, W2l, W2r, b2, hl2, out);

    k_agg2 <<<(8 * NN + 255) / 256, 256, 0, stream>>>(
        rowptr, col, (const float2*)hl2, (float2*)out);
}

// Round 5
// 200.604 us; speedup vs baseline: 2.2652x; 1.0438x over previous
//
#include <hip/hip_runtime.h>
#include <hip/hip_bf16.h>

static constexpr int NN = 50000;   // nodes
static constexpr int NE = 800000;  // edges
static constexpr int CH = 64;      // in/hidden channels
static constexpr int NB = (NN + 255) / 256;   // 196 scan blocks

// ---------------- x -> bf16 copy (gather-bandwidth halver) ------------------
__global__ __launch_bounds__(256) void k_cvt(const float* __restrict__ x,
                                             __hip_bfloat16* __restrict__ xb) {
    int t = blockIdx.x * 256 + threadIdx.x;
    int base = t * 4;
    if (base >= NN * CH) return;
    float4 v = *(const float4*)(x + base);
    xb[base + 0] = __float2bfloat16(v.x);
    xb[base + 1] = __float2bfloat16(v.y);
    xb[base + 2] = __float2bfloat16(v.z);
    xb[base + 3] = __float2bfloat16(v.w);
}

// ---------------- degree histogram ----------------
__global__ __launch_bounds__(256) void k_deg(const int* __restrict__ dst,
                                             int* __restrict__ deg) {
    int e = blockIdx.x * 256 + threadIdx.x;
    if (e < NE) atomicAdd(&deg[dst[e]], 1);
}

// ---------------- scan phase 1: per-block sums ------------------------------
__global__ __launch_bounds__(256) void k_bsum(const int* __restrict__ deg,
                                              int* __restrict__ bs) {
    int i = blockIdx.x * 256 + threadIdx.x;
    int v = (i < NN) ? deg[i] : 0;
#pragma unroll
    for (int off = 32; off > 0; off >>= 1) v += __shfl_xor(v, off);
    __shared__ int ws[4];
    if ((threadIdx.x & 63) == 0) ws[threadIdx.x >> 6] = v;
    __syncthreads();
    if (threadIdx.x == 0) bs[blockIdx.x] = ws[0] + ws[1] + ws[2] + ws[3];
}

// ---------------- scan phase 2: exclusive scan of the 196 block sums --------
__global__ __launch_bounds__(256) void k_bscan(int* __restrict__ bs) {
    int tid = threadIdx.x, lane = tid & 63, w = tid >> 6;
    __shared__ int wsum[4];
    int v = (tid < NB) ? bs[tid] : 0;
    int s = v;
#pragma unroll
    for (int off = 1; off < 64; off <<= 1) {
        int t = __shfl_up(s, off);
        if (lane >= off) s += t;
    }
    if (lane == 63) wsum[w] = s;
    __syncthreads();
    if (tid == 0) {
        int c = 0;
#pragma unroll
        for (int k = 0; k < 4; ++k) { int t = wsum[k]; wsum[k] = c; c += t; }
    }
    __syncthreads();
    if (tid < NB) bs[tid] = wsum[w] + s - v;   // exclusive offsets
}

// ---------------- scan phase 3: block rescan -> rowptr / cursor -------------
__global__ __launch_bounds__(256) void k_rescan(const int* __restrict__ deg,
                                                const int* __restrict__ bs,
                                                int* __restrict__ rowptr,
                                                int* __restrict__ cursor) {
    int tid = threadIdx.x, lane = tid & 63, w = tid >> 6;
    int i = blockIdx.x * 256 + tid;
    __shared__ int wsum[4];
    int v = (i < NN) ? deg[i] : 0;
    int s = v;
#pragma unroll
    for (int off = 1; off < 64; off <<= 1) {
        int t = __shfl_up(s, off);
        if (lane >= off) s += t;
    }
    if (lane == 63) wsum[w] = s;
    __syncthreads();
    if (tid == 0) {
        int c = 0;
#pragma unroll
        for (int k = 0; k < 4; ++k) { int t = wsum[k]; wsum[k] = c; c += t; }
    }
    __syncthreads();
    if (i < NN) {
        int excl = bs[blockIdx.x] + wsum[w] + s - v;
        rowptr[i] = excl;
        cursor[i] = excl;
    }
    if (blockIdx.x == 0 && tid == 0) rowptr[NN] = NE;
}

// ---------------- bucket-place: col[] = src ids grouped by dst --------------
__global__ __launch_bounds__(256) void k_place(const int* __restrict__ src,
                                               const int* __restrict__ dst,
                                               int* __restrict__ cursor,
                                               int* __restrict__ col) {
    int e = blockIdx.x * 256 + threadIdx.x;
    if (e >= NE) return;
    int pos = atomicAdd(&cursor[dst[e]], 1);
    col[pos] = src[e];
}

// ---------------- layer-1 CSR mean-aggregate over bf16 x --------------------
// wave per node, lane = channel (2B/lane -> 128B coalesced row, 2 cache lines)
__global__ __launch_bounds__(256) void k_agg1(const int* __restrict__ rowptr,
                                              const int* __restrict__ col,
                                              const __hip_bfloat16* __restrict__ xb,
                                              float* __restrict__ mean) {
    const int node = blockIdx.x * 4 + (threadIdx.x >> 6);
    const int lane = threadIdx.x & 63;
    if (node >= NN) return;
    const int beg = rowptr[node], end = rowptr[node + 1];
    float acc = 0.0f;
    int i = beg;
    for (; i + 4 <= end; i += 4) {          // 4 gathers in flight
        int c0 = col[i + 0], c1 = col[i + 1], c2 = col[i + 2], c3 = col[i + 3];
        float v0 = __bfloat162float(xb[c0 * CH + lane]);
        float v1 = __bfloat162float(xb[c1 * CH + lane]);
        float v2 = __bfloat162float(xb[c2 * CH + lane]);
        float v3 = __bfloat162float(xb[c3 * CH + lane]);
        acc += (v0 + v1) + (v2 + v3);
    }
    for (; i < end; ++i) acc += __bfloat162float(xb[col[i] * CH + lane]);
    const float inv = (end > beg) ? 1.0f / (float)(end - beg) : 0.0f;
    mean[(size_t)node * CH + lane] = acc * inv;
}

// ---------------- fused: layer-1 finalize + layer-2 node-local projections --
// One wave per block, __launch_bounds__(64,2) -> VGPR cap 256 so the 128
// weight floats are truly register-resident (verify: VGPR_Count ~150-200).
// Node rows are wave-uniform -> scalar (s_load) reads. 4 independent
// accumulators break the FMA dependency chain.
__global__ __launch_bounds__(64, 2) void k_fused(
        const float* __restrict__ x, const float* __restrict__ mean,
        const float* __restrict__ W1l, const float* __restrict__ W1r,
        const float* __restrict__ b1,
        const float* __restrict__ W2l, const float* __restrict__ W2r,
        const float* __restrict__ b2,
        float* __restrict__ hl2, float* __restrict__ out) {
    const int lane = threadIdx.x;  // 0..63

    float4 wl[16], wr[16];
    const float4* wlp = (const float4*)(W1l + lane * CH);
    const float4* wrp = (const float4*)(W1r + lane * CH);
#pragma unroll
    for (int i = 0; i < 16; ++i) { wl[i] = wlp[i]; wr[i] = wrp[i]; }
    const float bias = b1[lane];
    const float w2l0 = W2l[lane], w2l1 = W2l[64 + lane];
    const float w2r0 = W2r[lane], w2r1 = W2r[64 + lane];
    const float b20 = b2[0], b21 = b2[1];

    constexpr int NPER = 8;
    const int n0 = blockIdx.x * NPER;
    const int n1 = min(n0 + NPER, NN);

    for (int n = n0; n < n1; ++n) {
        const float4* mr = (const float4*)(mean + (size_t)n * CH);  // uniform
        const float4* xr = (const float4*)(x + (size_t)n * CH);     // uniform
        float p0 = 0.f, p1 = 0.f, p2 = 0.f, p3 = 0.f;
#pragma unroll
        for (int i = 0; i < 16; ++i) {
            float4 m = mr[i];
            float4 v = xr[i];
            p0 = fmaf(m.x, wl[i].x, p0);
            p1 = fmaf(m.y, wl[i].y, p1);
            p2 = fmaf(m.z, wl[i].z, p2);
            p3 = fmaf(m.w, wl[i].w, p3);
            p0 = fmaf(v.x, wr[i].x, p0);
            p1 = fmaf(v.y, wr[i].y, p1);
            p2 = fmaf(v.z, wr[i].z, p2);
            p3 = fmaf(v.w, wr[i].w, p3);
        }
        const float h = fmaxf(((p0 + p1) + (p2 + p3)) + bias, 0.0f);  // relu

        float a0 = h * w2l0, a1 = h * w2l1, r0 = h * w2r0, r1 = h * w2r1;
#pragma unroll
        for (int off = 32; off > 0; off >>= 1) {
            a0 += __shfl_xor(a0, off);
            a1 += __shfl_xor(a1, off);
            r0 += __shfl_xor(r0, off);
            r1 += __shfl_xor(r1, off);
        }
        if (lane == 0) {
            *(float2*)(hl2 + (size_t)n * 2) = make_float2(a0, a1);
            *(float2*)(out + (size_t)n * 2) = make_float2(b20 + r0, b21 + r1);
        }
    }
}

// ---------------- layer-2 CSR mean-aggregate + add into out -----------------
__global__ __launch_bounds__(256) void k_agg2(const int* __restrict__ rowptr,
                                              const int* __restrict__ col,
                                              const float2* __restrict__ hl2,
                                              float2* __restrict__ out) {
    int t = blockIdx.x * 256 + threadIdx.x;
    int node = t >> 3;
    int sl = t & 7;
    if (node >= NN) return;
    const int beg = rowptr[node], end = rowptr[node + 1];
    float ax = 0.0f, ay = 0.0f;
    for (int i = beg + sl; i < end; i += 8) {
        float2 v = hl2[col[i]];
        ax += v.x; ay += v.y;
    }
#pragma unroll
    for (int off = 4; off > 0; off >>= 1) {
        ax += __shfl_xor(ax, off);
        ay += __shfl_xor(ay, off);
    }
    if (sl == 0) {
        const float inv = (end > beg) ? 1.0f / (float)(end - beg) : 0.0f;
        float2 o = out[node];
        o.x += ax * inv;
        o.y += ay * inv;
        out[node] = o;
    }
}

extern "C" void kernel_launch(void* const* d_in, const int* in_sizes, int n_in,
                              void* d_out, int out_size, void* d_ws, size_t ws_size,
                              hipStream_t stream) {
    const float* x   = (const float*)d_in[0];
    const int*   ei  = (const int*)d_in[1];
    const float* W1l = (const float*)d_in[2];
    const float* W1r = (const float*)d_in[3];
    const float* b1  = (const float*)d_in[4];
    const float* W2l = (const float*)d_in[5];
    const float* W2r = (const float*)d_in[6];
    const float* b2  = (const float*)d_in[7];
    float* out = (float*)d_out;

    const int* src = ei;        // edge_index[0, :]
    const int* dst = ei + NE;   // edge_index[1, :]

    // workspace layout
    char* ws = (char*)d_ws;
    int*   deg    = (int*)ws;                          // 50048
    int*   rowptr = deg + 50048;                       // 50001 (pad 50052)
    int*   cursor = rowptr + 50052;                    // 50048
    int*   bs     = cursor + 50048;                    // 256
    int*   col    = bs + 256;                          // NE
    float* mean   = (float*)(col + NE);                // NN*CH f32
    float* hl2    = mean + (size_t)NN * CH;            // NN*2 f32
    __hip_bfloat16* xbf = (__hip_bfloat16*)(hl2 + (size_t)NN * 2);  // NN*CH bf16

    hipMemsetAsync(deg, 0, 50048 * 4, stream);

    k_cvt   <<<(NN * CH / 4 + 255) / 256, 256, 0, stream>>>(x, xbf);
    k_deg   <<<(NE + 255) / 256, 256, 0, stream>>>(dst, deg);
    k_bsum  <<<NB, 256, 0, stream>>>(deg, bs);
    k_bscan <<<1, 256, 0, stream>>>(bs);
    k_rescan<<<NB, 256, 0, stream>>>(deg, bs, rowptr, cursor);
    k_place <<<(NE + 255) / 256, 256, 0, stream>>>(src, dst, cursor, col);
    k_agg1  <<<(NN + 3) / 4, 256, 0, stream>>>(rowptr, col, xbf, mean);

    constexpr int NPER = 8;
    k_fused<<<(NN + NPER - 1) / NPER, 64, 0, stream>>>(
        x, mean, W1l, W1r, b1, W2l, W2r, b2, hl2, out);

    k_agg2 <<<(8 * NN + 255) / 256, 256, 0, stream>>>(
        rowptr, col, (const float2*)hl2, (float2*)out);
}